// Round 1
// baseline (2154.919 us; speedup 1.0000x reference)
//
#include <hip/hip_runtime.h>
#include <hip/hip_bf16.h>

// ---------------------------------------------------------------------------
// VariLengthInputLayer on MI355X (gfx950)
// bs=16384, DIMS={2048,1024,512,1536,768,256} (sum 6144), NH=8, DK=DV=64, dm=512
//
// Math note: attn/|attn.min()| followed by row-L2-normalize cancels the global
// min exactly (norm(a/c)=norm(a)/c), so no device-wide reduction is needed.
//
// Precision: all GEMMs in fp16 MFMA (f32 accumulate). fp16 keeps logit errors
// ~5e-4 (bf16 would be ~8x worse); data is O(1) so fp16 range is safe.
//
// Dtype: harness may hand us fp32 or bf16 inputs. k_detect reinterprets the
// first 512 uint16 of input_data as bf16: fp32 low-halves produce huge
// exponents w.p. ~1, genuine bf16 N(0,1) stays < 10. Flag lives in ws.
//
// Workspace layout (bytes):
//   [0,256)                  flag
//   [256, 19398912)          Wh: all 18 proj weights + fc_w as fp16 (9699328 elems)
//   [19398912, 120062208)    Qh fp16 (16384*6*512)   -- later reused as Yh (fc out)
//   [120062208, 220725504)   Kh fp16                 -- later reused as Oh (attn@v out)
//   [220725504, 321388800)   Vh fp16
// Aliases are safe: Oh[b] is written by the same wave that first fully read
// Kh[b] (per-b slices, disjoint across blocks); Yh is written by the fc GEMM
// which runs after k_att consumed Qh (stream-serial kernels).
// ---------------------------------------------------------------------------

typedef _Float16 half8 __attribute__((ext_vector_type(8)));
typedef float floatx4 __attribute__((ext_vector_type(4)));

#define NSEG 6
#define LDA 6144
#define BS_TOT 16384
#define OUT0_ELEMS 50331648L  // 16384*6*512

__device__ __forceinline__ float bf_to_f(unsigned short u) {
  unsigned int w = ((unsigned int)u) << 16;
  return __uint_as_float(w);
}
__device__ __forceinline__ unsigned short f_to_bf(float f) {
  unsigned int u = __float_as_uint(f);
  u = (u + 0x7fffu + ((u >> 16) & 1u)) >> 16;  // RTNE
  return (unsigned short)u;
}
__device__ __forceinline__ float ld_any(const void* p, long i, int isbf) {
  return isbf ? bf_to_f(((const unsigned short*)p)[i]) : ((const float*)p)[i];
}
__device__ __forceinline__ void st_any(void* p, long i, float v, int isbf) {
  if (isbf) ((unsigned short*)p)[i] = f_to_bf(v);
  else      ((float*)p)[i] = v;
}

// ---------------- dtype detection ----------------
__global__ void k_detect(const unsigned short* x, int* flag) {
  __shared__ float sm[256];
  float m = 0.f;
  for (int i = threadIdx.x; i < 512; i += 256) {
    float v = fabsf(bf_to_f(x[i]));
    if (!(v < 1e30f)) v = 1e30f;  // NaN/Inf bit patterns -> definitely fp32 data
    m = fmaxf(m, v);
  }
  sm[threadIdx.x] = m;
  __syncthreads();
  for (int s = 128; s > 0; s >>= 1) {
    if (threadIdx.x < s) sm[threadIdx.x] = fmaxf(sm[threadIdx.x], sm[threadIdx.x + s]);
    __syncthreads();
  }
  if (threadIdx.x == 0) flag[0] = (sm[0] > 1e3f) ? 0 : 1;  // 0=fp32, 1=bf16
}

// ---------------- weights -> fp16 ----------------
struct PrepArgs {
  const void* src[19];
  int cs[20];  // cumulative element offsets (dest is packed in same order)
};
__global__ void k_prep(PrepArgs pa, _Float16* wh, const int* flag, int total) {
  int idx = blockIdx.x * 256 + threadIdx.x;
  if (idx >= total) return;
  int isbf = flag[0];
  int a = 0;
  while (pa.cs[a + 1] <= idx) ++a;
  wh[idx] = (_Float16)ld_any(pa.src[a], idx - pa.cs[a], isbf);
}

// ---------------- fp16 MFMA GEMM: C[M,N] = A[M,K] * W[N,K]^T ----------------
// Tile 128x64x64, 4 waves (2x2), each wave 64x32 via 4x2 16x16x32 MFMAs.
// Fragment layouts (m89/m91-verified, dtype-independent):
//   A/B operand: lane holds [mn = lane&15][k = (lane>>4)*8 + j], j=0..7
//   C/D: col = lane&15, row = (lane>>4)*4 + reg
struct GemmZ {
  const void* A;       // element type per amode
  const _Float16* W;   // N x K row-major fp16
  _Float16* C;         // output, row stride = ostride
  long colOff;         // column offset into A rows (elements)
  int K;
};
struct GemmP {
  GemmZ z[18];
  int lda, ostride, amode;  // amode: -1=read flag (0/1), 2=fp16
  const int* flag;
};

#define BM 128
#define BN 64
#define BKT 64

__launch_bounds__(256)
__global__ void k_gemm(GemmP p) {
  __shared__ _Float16 As[BM][BKT + 8];  // +8 halfs pad: row stride 144B, 2-way max (free)
  __shared__ _Float16 Bs[BN][BKT + 8];
  GemmZ g = p.z[blockIdx.z];
  int amode = p.amode;
  if (amode < 0) amode = p.flag[0] ? 1 : 0;
  const int tid = threadIdx.x;
  const int lane = tid & 63;
  const int wid = tid >> 6;
  const int wm = (wid >> 1) * 64;
  const int wn = (wid & 1) * 32;
  const int m0 = blockIdx.y * BM;
  const int n0 = blockIdx.x * BN;
  const int srow = tid >> 3;       // 0..31
  const int scol = (tid & 7) * 8;  // 0..56
  const int lr = lane & 15;
  const int lq = lane >> 4;
  floatx4 acc[4][2] = {};

  for (int k0 = 0; k0 < g.K; k0 += BKT) {
    // stage A (BM x BKT) with on-the-fly conversion to fp16
    for (int r = 0; r < 4; ++r) {
      int row = srow + r * 32;
      long gi = (long)(m0 + row) * p.lda + g.colOff + k0 + scol;
      half8 av;
      if (amode == 2) {
        av = *(const half8*)((const _Float16*)g.A + gi);
      } else if (amode == 1) {
        uint4 rawv = *(const uint4*)((const unsigned short*)g.A + gi);
        unsigned int wb[4] = {rawv.x, rawv.y, rawv.z, rawv.w};
        for (int t = 0; t < 4; ++t) {
          av[2 * t]     = (_Float16)__uint_as_float(wb[t] << 16);
          av[2 * t + 1] = (_Float16)__uint_as_float(wb[t] & 0xffff0000u);
        }
      } else {
        const float* ap = (const float*)g.A + gi;
        float4 f0 = *(const float4*)ap;
        float4 f1 = *(const float4*)(ap + 4);
        av[0] = (_Float16)f0.x; av[1] = (_Float16)f0.y;
        av[2] = (_Float16)f0.z; av[3] = (_Float16)f0.w;
        av[4] = (_Float16)f1.x; av[5] = (_Float16)f1.y;
        av[6] = (_Float16)f1.z; av[7] = (_Float16)f1.w;
      }
      *(half8*)&As[row][scol] = av;
    }
    // stage B (BN x BKT), already fp16
    for (int r = 0; r < 2; ++r) {
      int row = srow + r * 32;
      long gi = (long)(n0 + row) * g.K + k0 + scol;
      *(half8*)&Bs[row][scol] = *(const half8*)(g.W + gi);
    }
    __syncthreads();
    for (int kk = 0; kk < BKT; kk += 32) {
      half8 af[4], bfr[2];
      for (int mt = 0; mt < 4; ++mt)
        af[mt] = *(half8*)&As[wm + mt * 16 + lr][kk + lq * 8];
      for (int nt = 0; nt < 2; ++nt)
        bfr[nt] = *(half8*)&Bs[wn + nt * 16 + lr][kk + lq * 8];
      for (int mt = 0; mt < 4; ++mt)
        for (int nt = 0; nt < 2; ++nt)
          acc[mt][nt] = __builtin_amdgcn_mfma_f32_16x16x32_f16(af[mt], bfr[nt], acc[mt][nt], 0, 0, 0);
    }
    __syncthreads();
  }
  for (int mt = 0; mt < 4; ++mt)
    for (int nt = 0; nt < 2; ++nt)
      for (int r = 0; r < 4; ++r) {
        int mg = m0 + wm + mt * 16 + lq * 4 + r;
        int ng = n0 + wn + nt * 16 + lr;
        g.C[(long)mg * p.ostride + ng] = (_Float16)acc[mt][nt][r];
      }
}

// ---------------- fused attention (per batch row) ----------------
// 1 wave per batch b; block = 2 waves. logits -> L2-normalize -> softmax ->
// write attn to d_out -> o = attn @ v -> Oh (aliases Kh[b], read-before-write).
#define AWPB 2
__global__ void k_att(const _Float16* Qh, const _Float16* Kh, const _Float16* Vh,
                      _Float16* Oh, void* dout, const int* flag) {
  __shared__ __align__(16) _Float16 qs[AWPB][6 * 512];
  __shared__ __align__(16) _Float16 ks[AWPB][6 * 512];
  __shared__ __align__(16) _Float16 vs[AWPB][6 * 512];
  __shared__ float ss[AWPB][288];
  const int lane = threadIdx.x & 63;
  const int wv = threadIdx.x >> 6;
  const long b = (long)blockIdx.x * AWPB + wv;
  const int isbf = flag[0];
  {
    const uint4* qsrc = (const uint4*)(Qh + b * 3072);
    const uint4* ksrc = (const uint4*)(Kh + b * 3072);
    const uint4* vsrc = (const uint4*)(Vh + b * 3072);
    uint4* qd = (uint4*)qs[wv];
    uint4* kd = (uint4*)ks[wv];
    uint4* vd = (uint4*)vs[wv];
    for (int t = 0; t < 6; ++t) {
      int i = lane + 64 * t;  // 384 uint4 per buffer
      qd[i] = qsrc[i];
      kd[i] = ksrc[i];
      vd[i] = vsrc[i];
    }
  }
  __syncthreads();
  // raw logits s[h,i,j] = q[b,h,i,:].k[b,h,j,:] / 8
  for (int idx = lane; idx < 288; idx += 64) {
    int h = idx / 36, rem = idx % 36, i = rem / 6, j = rem % 6;
    const _Float16* qp = qs[wv] + i * 512 + h * 64;
    const _Float16* kp = ks[wv] + j * 512 + h * 64;
    float a = 0.f;
    for (int d = 0; d < 64; ++d) a += (float)qp[d] * (float)kp[d];
    ss[wv][idx] = a * 0.125f;
  }
  __syncthreads();
  // per (h,i) row: L2-normalize (global-min division cancels) + softmax
  if (lane < 48) {
    float* sp = ss[wv] + lane * 6;
    float n2 = 0.f;
    for (int j = 0; j < 6; ++j) n2 += sp[j] * sp[j];
    float inv = 1.0f / fmaxf(sqrtf(n2), 1e-12f);
    float mx = -1e30f;
    for (int j = 0; j < 6; ++j) mx = fmaxf(mx, sp[j] * inv);
    float sum = 0.f;
    for (int j = 0; j < 6; ++j) {
      float e = expf(sp[j] * inv - mx);
      sp[j] = e;
      sum += e;
    }
    float rcp = 1.0f / sum;
    for (int j = 0; j < 6; ++j) sp[j] *= rcp;
  }
  __syncthreads();
  // attn output (second return value), layout ((b*8+h)*6+i)*6+j = b*288+idx
  for (int idx = lane; idx < 288; idx += 64)
    st_any(dout, OUT0_ELEMS + b * 288 + idx, ss[wv][idx], isbf);
  // o[i, h*64+d] = sum_j attn[h,i,j] * v[j, h*64+d]
  for (int idx = lane; idx < 3072; idx += 64) {
    int i = idx >> 9, c = idx & 511, h = c >> 6;
    const float* ap = ss[wv] + h * 36 + i * 6;
    const _Float16* vp = vs[wv] + c;
    float o = 0.f;
    for (int j = 0; j < 6; ++j) o += ap[j] * (float)vp[j * 512];
    Oh[b * 3072 + idx] = (_Float16)o;
  }
}

// ---------------- bias + residual + LayerNorm ----------------
__global__ void k_epi(const _Float16* Yh, const _Float16* Vh, const void* fcb,
                      const void* lng, const void* lnb, void* dout, const int* flag) {
  const int lane = threadIdx.x & 63;
  const int wv = threadIdx.x >> 6;
  const long r = (long)blockIdx.x * 4 + wv;  // row in [0, 98304)
  const int isbf = flag[0];
  const _Float16* yp = Yh + r * 512;
  const _Float16* vp = Vh + r * 512;
  float x[8];
  float s = 0.f, s2 = 0.f;
  for (int j = 0; j < 8; ++j) {
    int c = lane + 64 * j;
    float v = (float)yp[c] + (float)vp[c] + ld_any(fcb, c, isbf);
    x[j] = v;
    s += v;
    s2 += v * v;
  }
  for (int off = 32; off > 0; off >>= 1) {
    s += __shfl_xor(s, off);
    s2 += __shfl_xor(s2, off);
  }
  float mu = s * (1.0f / 512.0f);
  float var = s2 * (1.0f / 512.0f) - mu * mu;
  float rs = 1.0f / sqrtf(var + 1e-6f);
  for (int j = 0; j < 8; ++j) {
    int c = lane + 64 * j;
    float v = (x[j] - mu) * rs * ld_any(lng, c, isbf) + ld_any(lnb, c, isbf);
    st_any(dout, r * 512 + c, v, isbf);
  }
}

// ---------------- host launcher ----------------
extern "C" void kernel_launch(void* const* d_in, const int* in_sizes, int n_in,
                              void* d_out, int out_size, void* d_ws, size_t ws_size,
                              hipStream_t stream) {
  static const int dims[NSEG] = {2048, 1024, 512, 1536, 768, 256};
  static const int offs[NSEG] = {0, 2048, 3072, 3584, 5120, 5888};
  char* ws = (char*)d_ws;
  int* flag = (int*)ws;
  _Float16* Wh = (_Float16*)(ws + 256);
  _Float16* Qh = (_Float16*)(ws + 19398912L);
  _Float16* Kh = (_Float16*)(ws + 120062208L);
  _Float16* Vh = (_Float16*)(ws + 220725504L);
  _Float16* Oh = Kh;  // alias: per-b read-before-write inside k_att
  _Float16* Yh = Qh;  // alias: Qh dead after k_att

  k_detect<<<1, 256, 0, stream>>>((const unsigned short*)d_in[0], flag);

  PrepArgs pa;
  int c = 0;
  for (int a = 0; a < 19; ++a) {
    pa.src[a] = d_in[1 + a];  // wq0,wk0,wv0,...,wv5, fc_w
    pa.cs[a] = c;
    c += (a < 18) ? 512 * dims[a / 3] : 512 * 512;
  }
  pa.cs[19] = c;  // 9699328 total elems
  k_prep<<<(c + 255) / 256, 256, 0, stream>>>(pa, Wh, flag, c);

  // 18 projection GEMMs: z = seg*3 + {q,k,v}
  GemmP g1;
  g1.lda = LDA;
  g1.ostride = 3072;  // out[b][seg][n] with n-stride 1, seg-stride 512
  g1.amode = -1;
  g1.flag = flag;
  for (int z = 0; z < 18; ++z) {
    int seg = z / 3, t = z % 3;
    g1.z[z].A = d_in[0];
    g1.z[z].colOff = offs[seg];
    g1.z[z].W = Wh + pa.cs[z];
    g1.z[z].K = dims[seg];
    _Float16* base = (t == 0) ? Qh : (t == 1) ? Kh : Vh;
    g1.z[z].C = base + seg * 512;
  }
  k_gemm<<<dim3(8, BS_TOT / BM, 18), 256, 0, stream>>>(g1);

  k_att<<<BS_TOT / AWPB, 64 * AWPB, 0, stream>>>(Qh, Kh, Vh, Oh, d_out, flag);

  // fc GEMM: (98304 x 512) @ fc_w^T
  GemmP g2;
  g2.lda = 512;
  g2.ostride = 512;
  g2.amode = 2;
  g2.flag = flag;
  g2.z[0].A = Oh;
  g2.z[0].colOff = 0;
  g2.z[0].W = Wh + pa.cs[18];
  g2.z[0].K = 512;
  g2.z[0].C = Yh;
  for (int z = 1; z < 18; ++z) g2.z[z] = g2.z[0];
  k_gemm<<<dim3(8, 98304 / BM, 1), 256, 0, stream>>>(g2);

  k_epi<<<98304 / 4, 256, 0, stream>>>(Yh, Vh, d_in[20], d_in[21], d_in[22], d_out, flag);
}